// Round 19
// baseline (26319.516 us; speedup 1.0000x reference)
//
#include <hip/hip_runtime.h>
#include <stdint.h>
#include <stddef.h>

// GRU (B=32, T=2048, I=H=512, fp32 in/out).
// Phase 1 (MFMA GEMM): gz|gr -> fp16 INTO d_out (row-aliased); gh -> d_ws.
// Phase 2 (R19 = R16 + XCC-verified grouping + intra-L2 exchange):
//   256 WGs, D=1 lean step (conflict-free b128 weight LDS, 8-lane shuffle
//   z/r reduce, 2 barriers, fp16 P u32 + f32 z u64 tagged exchange).
//   NEW: each WG reads its REAL XCD via s_getreg(HW_REG_XCC_ID) and CAS-claims
//   a (batch,slice) entry from that XCD's partition -> the 8 slices of a batch
//   provably share one L2. Exchange: sc0 store (updates shared L2) + agent
//   store (fabric, correctness under any placement); polls are sc0 loads
//   (L1-bypass, L2-hit) with an agent escape every 16th round (no-hang).
//   R10 used these primitives but with UNVERIFIED bid&7 grouping -> cross-XCD
//   placement made sc0 polls spin on stale consumer-L2 lines; claims fix that.
// Fallback (!gh_mode): R8 scalar scan.

#define AGENT __HIP_MEMORY_SCOPE_AGENT

typedef _Float16 h2v __attribute__((ext_vector_type(2)));
typedef _Float16 half8 __attribute__((ext_vector_type(8)));
typedef float f32x4 __attribute__((ext_vector_type(4)));

__device__ __forceinline__ uint32_t pk2u(float a, float b) {
  h2v r; r[0] = (_Float16)a; r[1] = (_Float16)b;
  return __builtin_bit_cast(uint32_t, r);
}
__device__ __forceinline__ h2v bc2(uint32_t u) { return __builtin_bit_cast(h2v, u); }
__device__ __forceinline__ float dot2f(h2v a, h2v b, float c) {
#if __has_builtin(__builtin_amdgcn_fdot2)
  return __builtin_amdgcn_fdot2(a, b, c, false);
#else
  return fmaf((float)a[1], (float)b[1], fmaf((float)a[0], (float)b[0], c));
#endif
}
__device__ __forceinline__ float sigmoidf_(float x) { return 1.0f / (1.0f + __expf(-x)); }
__device__ __forceinline__ float tanhf_(float x) { return 1.0f - 2.0f / (1.0f + __expf(2.0f * x)); }

__device__ __forceinline__ uint32_t ald32a(const uint32_t* p) {
  return __hip_atomic_load(p, __ATOMIC_RELAXED, AGENT);
}
__device__ __forceinline__ uint64_t ald64a(const uint64_t* p) {
  return __hip_atomic_load(p, __ATOMIC_RELAXED, AGENT);
}
__device__ __forceinline__ void ast64a(uint64_t* p, uint64_t v) {
  __hip_atomic_store(p, v, __ATOMIC_RELAXED, AGENT);
}
__device__ __forceinline__ float f16b2f(uint32_t w) {
  return (float)__builtin_bit_cast(_Float16, (unsigned short)(w & 0xffffu));
}

// ---- intra-L2 (sc0) exchange primitives (R10-compiled patterns) ----
__device__ __forceinline__ uint32_t ld32_sc0(const uint32_t* p) {
  uint32_t v;
  asm volatile("global_load_dword %0, %1, off sc0\n\ts_waitcnt vmcnt(0)"
               : "=v"(v) : "v"(p) : "memory");
  return v;
}
__device__ __forceinline__ uint64_t ld64_sc0(const uint64_t* p) {
  uint64_t v;
  asm volatile("global_load_dwordx2 %0, %1, off sc0\n\ts_waitcnt vmcnt(0)"
               : "=v"(v) : "v"(p) : "memory");
  return v;
}
__device__ __forceinline__ void st32_pub(uint32_t* p, uint32_t v) {
  asm volatile("global_store_dword %0, %1, off sc0" :: "v"(p), "v"(v) : "memory");
  __hip_atomic_store(p, v, __ATOMIC_RELAXED, AGENT);  // fabric (correctness)
}
__device__ __forceinline__ void st64_pub(uint64_t* p, uint64_t v) {
  asm volatile("global_store_dwordx2 %0, %1, off sc0" :: "v"(p), "v"(v) : "memory");
  __hip_atomic_store(p, v, __ATOMIC_RELAXED, AGENT);
}
// batched prime: 8 P words (u32, stride 512) + 1 z word (u64), one waitcnt
__device__ __forceinline__ void ld9_sc0(const uint32_t* pP, const uint64_t* pz,
                                        uint32_t v[8], uint64_t& zv) {
  asm volatile(
      "global_load_dword %0, %9, off sc0\n\t"
      "global_load_dword %1, %10, off sc0\n\t"
      "global_load_dword %2, %11, off sc0\n\t"
      "global_load_dword %3, %12, off sc0\n\t"
      "global_load_dword %4, %13, off sc0\n\t"
      "global_load_dword %5, %14, off sc0\n\t"
      "global_load_dword %6, %15, off sc0\n\t"
      "global_load_dword %7, %16, off sc0\n\t"
      "global_load_dwordx2 %8, %17, off sc0\n\t"
      "s_waitcnt vmcnt(0)"
      : "=&v"(v[0]), "=&v"(v[1]), "=&v"(v[2]), "=&v"(v[3]),
        "=&v"(v[4]), "=&v"(v[5]), "=&v"(v[6]), "=&v"(v[7]), "=&v"(zv)
      : "v"(pP), "v"(pP + 512), "v"(pP + 1024), "v"(pP + 1536),
        "v"(pP + 2048), "v"(pP + 2560), "v"(pP + 3072), "v"(pP + 3584),
        "v"(pz)
      : "memory");
}

// ---------------- Phase 1: gate GEMM  [65536 x 512] @ [512 x N*128] -> fp16 ----------------
__global__ __launch_bounds__(256) void gemm_gx(const float* __restrict__ x,
                                               const float* __restrict__ Wx,
                                               const float* __restrict__ bias,
                                               _Float16* gzr,   // [65536][1024] (aliases out)
                                               _Float16* gh,    // [65536][512] in ws (opt)
                                               int nTN) {
  __shared__ alignas(16) _Float16 Alds[128 * 68];
  __shared__ alignas(16) _Float16 Blds[128 * 68];
  const int tid = threadIdx.x;
  const int bid = blockIdx.x;
  const int tm = bid / nTN, tn = bid % nTN;
  const int m0 = tm << 7, n0 = tn << 7;
  const int lane = tid & 63;
  const int wv = tid >> 6, wm = wv >> 1, wn = wv & 1;
  const int l15 = lane & 15, lhi = lane >> 4;
  f32x4 acc[4][4] = {};

  for (int k0 = 0; k0 < 512; k0 += 64) {
#pragma unroll
    for (int r = 0; r < 8; ++r) {
      int m = r * 16 + (tid >> 4);
      int k = (tid & 15) * 4;
      float4 v = *(const float4*)&x[(size_t)(m0 + m) * 512 + k0 + k];
      union { _Float16 h[4]; uint2 u; } cv;
      cv.h[0] = (_Float16)v.x; cv.h[1] = (_Float16)v.y;
      cv.h[2] = (_Float16)v.z; cv.h[3] = (_Float16)v.w;
      *(uint2*)&Alds[m * 68 + k] = cv.u;
    }
#pragma unroll
    for (int u = 0; u < 8; ++u) {
      int n = tid & 127;
      int k = (tid >> 7) * 32 + u * 4;
      int ng = n0 + n;
      const float* wp = Wx + ((size_t)(ng >> 9) << 18) + (size_t)(k0 + k) * 512 + (ng & 511);
      union { _Float16 h[4]; uint2 u2; } cv;
      cv.h[0] = (_Float16)wp[0];    cv.h[1] = (_Float16)wp[512];
      cv.h[2] = (_Float16)wp[1024]; cv.h[3] = (_Float16)wp[1536];
      *(uint2*)&Blds[n * 68 + k] = cv.u2;
    }
    __syncthreads();
#pragma unroll
    for (int kk = 0; kk < 2; ++kk) {
      int q = kk * 4 + lhi;
      half8 af[4], bf[4];
#pragma unroll
      for (int fm = 0; fm < 4; ++fm) {
        const _Float16* pa = &Alds[(wm * 64 + fm * 16 + l15) * 68 + q * 8];
        union { uint2 u[2]; half8 h; } cv;
        cv.u[0] = *(const uint2*)pa; cv.u[1] = *(const uint2*)(pa + 4);
        af[fm] = cv.h;
      }
#pragma unroll
      for (int fn = 0; fn < 4; ++fn) {
        const _Float16* pb = &Blds[(wn * 64 + fn * 16 + l15) * 68 + q * 8];
        union { uint2 u[2]; half8 h; } cv;
        cv.u[0] = *(const uint2*)pb; cv.u[1] = *(const uint2*)(pb + 4);
        bf[fn] = cv.h;
      }
#pragma unroll
      for (int fm = 0; fm < 4; ++fm)
#pragma unroll
        for (int fn = 0; fn < 4; ++fn)
          acc[fm][fn] = __builtin_amdgcn_mfma_f32_16x16x32_f16(af[fm], bf[fn], acc[fm][fn], 0, 0, 0);
    }
    __syncthreads();
  }
#pragma unroll
  for (int fn = 0; fn < 4; ++fn) {
    int col = n0 + wn * 64 + fn * 16 + l15;
    float bv = bias[col];
#pragma unroll
    for (int fm = 0; fm < 4; ++fm) {
#pragma unroll
      for (int q2 = 0; q2 < 4; ++q2) {
        int row = m0 + wm * 64 + fm * 16 + lhi * 4 + q2;
        _Float16 val = (_Float16)(acc[fm][fn][q2] + bv);
        if (n0 < 1024) gzr[(size_t)row * 1024 + col] = val;
        else           gh[(size_t)row * 512 + (col - 1024)] = val;
      }
    }
  }
}

// ---------------- Phase 2 (R19): lean D=1 scan, XCC-grouped intra-L2 exchange ----------------
__device__ __forceinline__ bool tagsok9(const uint32_t pv[8], uint64_t zv, uint32_t want) {
  bool ok = ((uint32_t)(zv >> 32) == want);
#pragma unroll
  for (int q = 0; q < 8; ++q) ok &= ((pv[q] >> 16) == want);
  return ok;
}

__global__ __launch_bounds__(512) void gru_scan3(
    const _Float16* gzr,            // [65536][1024] (aliases out!)
    const _Float16* ghg,            // [65536][512]
    const float* __restrict__ Wh,   // [3][512][512]
    float* out,                     // [32][2048][512] + [32][512]
    uint32_t* __restrict__ Pbuf,    // [2][32][8 slice][512 col] u32 {tag16|fp16}
    uint64_t* __restrict__ zbuf,    // [2][32][512] u64 {tag32|f32}
    uint32_t* __restrict__ cnt,     // [8] per-XCD claim counters
    uint32_t* __restrict__ claim) { // [256] entry claim flags
  __shared__ alignas(16) _Float16 wzK[2 * 8 * 64 * 8 * 8];  // 128 KB
  __shared__ alignas(16) _Float16 hA[512];
  __shared__ alignas(16) _Float16 rh[64];
  __shared__ int entryS;

  const int T = threadIdx.x;

  // ---- XCC-verified (batch, slice) claim ----
  if (T == 0) {
    uint32_t xcd;
    asm volatile("s_getreg_b32 %0, hwreg(HW_REG_XCC_ID)" : "=s"(xcd));
    xcd &= 7u;
    uint32_t slot = __hip_atomic_fetch_add(&cnt[xcd], 1u, __ATOMIC_RELAXED, AGENT);
    int entry = -1;
    if (slot < 32u) {
      int e = (int)(xcd * 32u + slot);
      uint32_t exp0 = 0;
      if (__hip_atomic_compare_exchange_strong(&claim[e], &exp0, 1u,
                                               __ATOMIC_RELAXED, __ATOMIC_RELAXED, AGENT))
        entry = e;
    }
    if (entry < 0) {  // spill: CAS-scan (correctness never depends on placement)
      int e = (int)(xcd * 32u);
      while (entry < 0) {
        if (__hip_atomic_load(&claim[e], __ATOMIC_RELAXED, AGENT) == 0u) {
          uint32_t exp0 = 0;
          if (__hip_atomic_compare_exchange_strong(&claim[e], &exp0, 1u,
                                                   __ATOMIC_RELAXED, __ATOMIC_RELAXED, AGENT))
            entry = e;
        }
        e = (e + 1) & 255;
      }
    }
    entryS = entry;
  }
  __syncthreads();
  const int entry = entryS;
  const int s = entry & 7;                              // slice
  const int b = ((entry >> 5) << 2) + ((entry >> 3) & 3);  // batch (bijective)

  const int c = T >> 3, sub = T & 7;
  const int gcol = s * 64 + c;

  // ---- weight fill: wzK (g,cc,col,sub)[e] = W_g[(cc*8+sub)*8+e][s*64+col] ----
  for (int g = 0; g < 2; ++g) {
    const float* W = Wh + (size_t)g * 262144;
    for (int idx = T; idx < 4096; idx += 512) {
      int cc = idx >> 9;
      int col = (idx >> 3) & 63;
      int sb = idx & 7;
      int kbase = (cc * 8 + sb) * 8;
      _Float16* dst = &wzK[(((g * 8 + cc) * 64 + col) * 8 + sb) * 8];
#pragma unroll
      for (int e = 0; e < 8; ++e)
        dst[e] = (_Float16)W[(size_t)(kbase + e) * 512 + s * 64 + col];
    }
  }
  // ---- candidate weights: 32 u32/thread (K rows = own 64 cols) ----
  uint32_t wh2[32];
  {
    const float* Whh = Wh + 524288;
#pragma unroll
    for (int i = 0; i < 32; ++i) {
      int kk = s * 64 + 2 * i;
      wh2[i] = pk2u(Whh[(size_t)kk * 512 + T], Whh[(size_t)(kk + 1) * 512 + T]);
    }
  }
  hA[T] = (_Float16)0.0f;
  float hreg = 0.f;

  const size_t rb = (size_t)b * 2048;
  float gh_p, gh_c = 0.f, gz_p = 0.f, gr_p = 0.f, gz_c = 0.f, gr_c = 0.f;
  gh_p = (float)ghg[rb * 512 + T];
  if (sub == 0) {
    gz_p = (float)gzr[rb * 1024 + gcol];
    gr_p = (float)gzr[rb * 1024 + 512 + gcol];
  }

  uint32_t* Pm = Pbuf + ((size_t)b * 8 + s) * 512 + T;  // + par*131072 (coalesced)
  const uint32_t* Pr = Pbuf + (size_t)b * 4096 + T;     // slice q at +q*512
  uint64_t* zm = zbuf + (size_t)b * 512 + gcol;         // + par*16384 (sub==0)
  const uint64_t* zrd = zbuf + (size_t)b * 512 + T;

  uint32_t pv[8];
  uint64_t zv = 0;
#pragma unroll
  for (int q = 0; q < 8; ++q) pv[q] = 0;

  for (int t = 0; t < 2048; ++t) {
    const size_t poC = ((t - 1) & 1) ? 131072 : 0;
    const size_t zoC = ((t - 1) & 1) ? 16384 : 0;
    const size_t poN = (t & 1) ? 131072 : 0;
    const size_t zoN = (t & 1) ? 16384 : 0;
    const uint32_t want = (uint32_t)t;
    const uint32_t tagN = (uint32_t)(t + 1);

    // ---- combine step t-1 (pv/zv primed at end of previous iter) ----
    if (t > 0) {
      int round = 0;
      while (!tagsok9(pv, zv, want)) {
        ++round;
        __builtin_amdgcn_s_sleep(1);
        bool deep = (round & 15) == 15;  // agent escape: no-hang under any placement
        if ((uint32_t)(zv >> 32) != want)
          zv = deep ? ald64a(zrd + zoC) : ld64_sc0(zrd + zoC);
#pragma unroll
        for (int q = 0; q < 8; ++q)
          if ((pv[q] >> 16) != want) {
            const uint32_t* p = Pr + poC + (size_t)q * 512;
            pv[q] = deep ? ald32a(p) : ld32_sc0(p);
          }
      }
      float hsum = 0.f;
#pragma unroll
      for (int q = 0; q < 8; ++q) hsum += f16b2f(pv[q]);
      float zf = __uint_as_float((uint32_t)zv);
      float htil = tanhf_(gh_c + hsum);
      float hn = fmaf(zf, htil - hreg, hreg);
      if (s == 0) out[(rb + (t - 1)) * 512 + T] = hn;
      hreg = hn;
      hA[T] = (_Float16)hn;
    }
    gh_c = gh_p;
    gz_c = gz_p;
    gr_c = gr_p;
    __syncthreads();  // B1: hA(t-1) visible
    if (t < 2047) {
      size_t r1 = rb + t + 1;
      gh_p = (float)ghg[r1 * 512 + T];
      if (sub == 0) {
        gz_p = (float)gzr[r1 * 1024 + gcol];
        gr_p = (float)gzr[r1 * 1024 + 512 + gcol];
      }
    }

    // ---- z/r GEMV: thread (c,sub) covers K rows {(cc*8+sub)*8..+8, cc=0..7} ----
    float za = 0.f, ra = 0.f;
#pragma unroll
    for (int cc = 0; cc < 8; ++cc) {
      uint4 hu = *(const uint4*)&hA[(cc * 8 + sub) * 8];
      uint4 wz = *(const uint4*)&wzK[(((cc)*64 + c) * 8 + sub) * 8];
      uint4 wr = *(const uint4*)&wzK[(((8 + cc) * 64 + c) * 8 + sub) * 8];
      za = dot2f(bc2(hu.x), bc2(wz.x), za); za = dot2f(bc2(hu.y), bc2(wz.y), za);
      za = dot2f(bc2(hu.z), bc2(wz.z), za); za = dot2f(bc2(hu.w), bc2(wz.w), za);
      ra = dot2f(bc2(hu.x), bc2(wr.x), ra); ra = dot2f(bc2(hu.y), bc2(wr.y), ra);
      ra = dot2f(bc2(hu.z), bc2(wr.z), ra); ra = dot2f(bc2(hu.w), bc2(wr.w), ra);
    }
#pragma unroll
    for (int d = 1; d < 8; d <<= 1) {
      za += __shfl_xor(za, d);
      ra += __shfl_xor(ra, d);
    }
    if (sub == 0) {
      float z = sigmoidf_(za + gz_c);
      float r = sigmoidf_(ra + gr_c);
      rh[c] = (_Float16)(r * (float)hA[gcol]);
      st64_pub(zm + zoN, ((uint64_t)tagN << 32) | (uint32_t)__float_as_uint(z));
    }
    __syncthreads();  // B2: rh ready

    // ---- candidate K-slice (own 64 rows) -> publish P (coalesced u32) ----
    {
      float pa = 0.f;
#pragma unroll
      for (int i = 0; i < 16; ++i) {
        uint2 ru = *(const uint2*)&rh[4 * i];  // broadcast
        pa = dot2f(bc2(ru.x), bc2(wh2[2 * i]), pa);
        pa = dot2f(bc2(ru.y), bc2(wh2[2 * i + 1]), pa);
      }
      unsigned short pb = __builtin_bit_cast(unsigned short, (_Float16)pa);
      st32_pub(Pm + poN, (tagN << 16) | (uint32_t)pb);
    }
    // prime next combine (batched sc0, single waitcnt)
    ld9_sc0(Pr + poN, zrd + zoN, pv, zv);
    __builtin_amdgcn_sched_barrier(0);
  }

  // ---- epilogue: combine step 2047 (parity 1, tag 2048) ----
  {
    const uint32_t want = 2048u;
    int round = 0;
    while (!tagsok9(pv, zv, want)) {
      ++round;
      __builtin_amdgcn_s_sleep(1);
      bool deep = (round & 15) == 15;
      if ((uint32_t)(zv >> 32) != want)
        zv = deep ? ald64a(zrd + 16384) : ld64_sc0(zrd + 16384);
#pragma unroll
      for (int q = 0; q < 8; ++q)
        if ((pv[q] >> 16) != want) {
          const uint32_t* p = Pr + 131072 + (size_t)q * 512;
          pv[q] = deep ? ald32a(p) : ld32_sc0(p);
        }
    }
    float hsum = 0.f;
#pragma unroll
    for (int q = 0; q < 8; ++q) hsum += f16b2f(pv[q]);
    float zf = __uint_as_float((uint32_t)zv);
    float htil = tanhf_(gh_c + hsum);
    float hn = fmaf(zf, htil - hreg, hreg);
    if (s == 0) {
      out[(rb + 2047) * 512 + T] = hn;
      out[(size_t)32 * 2048 * 512 + (size_t)b * 512 + T] = hn;
    }
  }
}

// ---------------- Fallback scan (R8 scalar, !gh_mode) ----------------
__global__ __launch_bounds__(512) void gru_scan_fb(
    const float* __restrict__ x, const float* __restrict__ Wx,
    const float* __restrict__ Wh, const float* __restrict__ bias,
    const _Float16* gzr, float* out,
    uint64_t* __restrict__ Pbuf, uint64_t* __restrict__ zbuf) {
  __shared__ alignas(16) float zrp[2][8][64];
  __shared__ alignas(16) _Float16 wzrL[2 * 64 * 516];
  __shared__ alignas(16) _Float16 h16[512];
  __shared__ alignas(16) _Float16 rh16[64];
  __shared__ alignas(16) _Float16 x16s[64];

  const int T = threadIdx.x;
  const int bid = blockIdx.x;
  const int xcd = bid & 7, ii = bid >> 3;
  const int batch = xcd * 4 + (ii >> 3);
  const int slice = ii & 7;
  const int wv = T >> 6, ln = T & 63, n = T;
  {
    const int cc = T & 63, kb = T >> 6;
#pragma unroll 4
    for (int g = 0; g < 2; ++g) {
      const float* W = Wh + (size_t)g * 262144 + slice * 64 + cc;
      for (int i = 0; i < 64; ++i) {
        int k = kb + 8 * i;
        wzrL[(g * 64 + cc) * 516 + k] = (_Float16)W[(size_t)k * 512];
      }
    }
  }
  uint32_t wh2[32], wx2[32];
  {
    const float* Whh = Wh + 524288;
    const float* Wxh = Wx + 524288;
#pragma unroll
    for (int jj = 0; jj < 32; ++jj) {
      int kk = slice * 64 + 2 * jj;
      wh2[jj] = pk2u(Whh[(size_t)kk * 512 + n], Whh[(size_t)(kk + 1) * 512 + n]);
      wx2[jj] = pk2u(Wxh[(size_t)kk * 512 + n], Wxh[(size_t)(kk + 1) * 512 + n]);
    }
  }
  const float bh = bias[1024 + n];
  float hreg = 0.0f;
  h16[T] = (_Float16)0.0f;
  const size_t rowbase = (size_t)batch * 2048;
  float gz_p = 0.f, gr_p = 0.f, gz_cur = 0.f, gr_cur = 0.f, x_p = 0.f;
  if (T < 64)       gz_p = (float)gzr[rowbase * 1024 + slice * 64 + T];
  else if (T < 128) gr_p = (float)gzr[rowbase * 1024 + 512 + slice * 64 + (T - 64)];
  if (T < 64) x_p = x[rowbase * 512 + slice * 64 + T];

  uint64_t* Pmine = Pbuf + ((size_t)batch * 8 + slice) * 512 + n;
  const uint64_t* Pread = Pbuf + ((size_t)batch * 8) * 512 + n;
  uint64_t* zmine = zbuf + (size_t)batch * 512 + slice * 64 + ln;
  const uint64_t* zread = zbuf + (size_t)batch * 512 + n;

  for (int t = 0; t < 2048; ++t) {
    if (t > 0) {
      const size_t po = ((t - 1) & 1) ? 131072 : 0;
      const size_t zo = ((t - 1) & 1) ? 16384 : 0;
      const uint32_t want = (uint32_t)t;
      uint64_t v[8];
#pragma unroll
      for (int g = 0; g < 8; ++g) v[g] = ald64a(Pread + po + (size_t)g * 512);
      uint64_t zvv = ald64a(zread + zo);
      for (;;) {
        bool ok = true;
        if ((uint32_t)(zvv >> 32) != want) { zvv = ald64a(zread + zo); ok = false; }
#pragma unroll
        for (int g = 0; g < 8; ++g)
          if ((uint32_t)(v[g] >> 32) != want) { v[g] = ald64a(Pread + po + (size_t)g * 512); ok = false; }
        if (ok) break;
        __builtin_amdgcn_s_sleep(1);
      }
      float hsum = 0.f;
#pragma unroll
      for (int g = 0; g < 8; ++g) hsum += __uint_as_float((uint32_t)v[g]);
      float zf = __uint_as_float((uint32_t)zvv);
      float htil = tanhf_(bh + hsum);
      float hn = fmaf(zf, htil - hreg, hreg);
      if (slice == 0) out[(rowbase + (t - 1)) * 512 + n] = hn;
      hreg = hn;
      h16[T] = (_Float16)hn;
    }
    gz_cur = gz_p; gr_cur = gr_p;
    if (T < 64) x16s[T] = (_Float16)x_p;
    __syncthreads();
    if (t < 2047) {
      size_t r1 = rowbase + t + 1;
      if (T < 64)       gz_p = (float)gzr[r1 * 1024 + slice * 64 + T];
      else if (T < 128) gr_p = (float)gzr[r1 * 1024 + 512 + slice * 64 + (T - 64)];
      if (T < 64) x_p = x[r1 * 512 + slice * 64 + T];
    }
    float za = 0.f, ra = 0.f;
    {
      const _Float16* wzp = &wzrL[ln * 516 + 64 * wv];
      const _Float16* wrp = &wzrL[(64 + ln) * 516 + 64 * wv];
      const _Float16* hp = &h16[64 * wv];
#pragma unroll
      for (int jj = 0; jj < 16; ++jj) {
        uint2 wzu = *(const uint2*)(wzp + 4 * jj);
        uint2 wru = *(const uint2*)(wrp + 4 * jj);
        uint2 hu = *(const uint2*)(hp + 4 * jj);
        za = dot2f(bc2(hu.x), bc2(wzu.x), za);
        za = dot2f(bc2(hu.y), bc2(wzu.y), za);
        ra = dot2f(bc2(hu.x), bc2(wru.x), ra);
        ra = dot2f(bc2(hu.y), bc2(wru.y), ra);
      }
    }
    zrp[0][wv][ln] = za;
    zrp[1][wv][ln] = ra;
    __syncthreads();
    const size_t po = (t & 1) ? 131072 : 0;
    const size_t zo = (t & 1) ? 16384 : 0;
    const uint64_t tagw = ((uint64_t)(uint32_t)(t + 1)) << 32;
    if (T < 128) {
      const int g = T >> 6, cc = T & 63;
      float sum = 0.f;
#pragma unroll
      for (int s2 = 0; s2 < 8; ++s2) sum += zrp[g][s2][cc];
      if (g == 0) {
        float z = sigmoidf_(sum + gz_cur);
        ast64a(zmine + zo, tagw | (uint32_t)__float_as_uint(z));
      } else {
        float r = sigmoidf_(sum + gr_cur);
        rh16[cc] = (_Float16)(r * (float)h16[slice * 64 + cc]);
      }
    }
    __syncthreads();
    float pa = 0.f;
#pragma unroll
    for (int jj = 0; jj < 16; ++jj) {
      uint2 ru = *(const uint2*)&rh16[4 * jj];
      pa = dot2f(bc2(ru.x), bc2(wh2[2 * jj]), pa);
      pa = dot2f(bc2(ru.y), bc2(wh2[2 * jj + 1]), pa);
    }
#pragma unroll
    for (int jj = 0; jj < 16; ++jj) {
      uint2 xu = *(const uint2*)&x16s[4 * jj];
      pa = dot2f(bc2(xu.x), bc2(wx2[2 * jj]), pa);
      pa = dot2f(bc2(xu.y), bc2(wx2[2 * jj + 1]), pa);
    }
    ast64a(Pmine + po, tagw | (uint32_t)__float_as_uint(pa));
    __syncthreads();
  }
  {
    const uint32_t want = 2048u;
    uint64_t v[8];
#pragma unroll
    for (int g = 0; g < 8; ++g) v[g] = ald64a(Pread + 131072 + (size_t)g * 512);
    uint64_t zvv = ald64a(zread + 16384);
    for (;;) {
      bool ok = true;
      if ((uint32_t)(zvv >> 32) != want) { zvv = ald64a(zread + 16384); ok = false; }
#pragma unroll
      for (int g = 0; g < 8; ++g)
        if ((uint32_t)(v[g] >> 32) != want) { v[g] = ald64a(Pread + 131072 + (size_t)g * 512); ok = false; }
      if (ok) break;
      __builtin_amdgcn_s_sleep(1);
    }
    float hsum = 0.f;
#pragma unroll
    for (int g = 0; g < 8; ++g) hsum += __uint_as_float((uint32_t)v[g]);
    float zf = __uint_as_float((uint32_t)zvv);
    float htil = tanhf_(bh + hsum);
    float hn = fmaf(zf, htil - hreg, hreg);
    if (slice == 0) {
      out[(rowbase + 2047) * 512 + n] = hn;
      out[(size_t)32 * 2048 * 512 + (size_t)batch * 512 + n] = hn;
    }
  }
}

extern "C" void kernel_launch(void* const* d_in, const int* in_sizes, int n_in,
                              void* d_out, int out_size, void* d_ws, size_t ws_size,
                              hipStream_t stream) {
  (void)in_sizes; (void)n_in; (void)out_size;
  const float* x    = (const float*)d_in[0];
  const float* Wx   = (const float*)d_in[1];
  const float* Wh   = (const float*)d_in[2];
  const float* bias = (const float*)d_in[3];
  float* out = (float*)d_out;
  char* ws = (char*)d_ws;

  // gh_mode: Pbuf u32 [2][32][8][512] = 1 MB | zbuf u64 [2][32][512] = 256 KB
  //          | cnt[8] @ 1310720 | claim[256] @ 1310752 | gh @ 2621440
  // fallback: Pbuf u64 2 MB | zbuf u64 @ 2097152
  uint32_t* Pbuf3 = (uint32_t*)ws;
  uint64_t* zbuf3 = (uint64_t*)(ws + 1048576);
  uint32_t* cnt   = (uint32_t*)(ws + 1310720);
  uint32_t* claim = (uint32_t*)(ws + 1310752);
  uint64_t* PbufF = (uint64_t*)ws;
  uint64_t* zbufF = (uint64_t*)(ws + 2097152);
  _Float16* gh    = (_Float16*)(ws + 2621440);

  hipMemsetAsync(ws, 0, 2621440, stream);  // reset tags + claims (replay-safe)
  const bool gh_mode = ws_size >= (size_t)2621440 + 67108864ull;
  if (gh_mode) {
    gemm_gx<<<512 * 12, 256, 0, stream>>>(x, Wx, bias, (_Float16*)d_out, gh, 12);
    gru_scan3<<<256, 512, 0, stream>>>((const _Float16*)d_out, gh, Wh, out,
                                       Pbuf3, zbuf3, cnt, claim);
  } else {
    gemm_gx<<<512 * 8, 256, 0, stream>>>(x, Wx, bias, (_Float16*)d_out, gh, 8);
    gru_scan_fb<<<256, 512, 0, stream>>>(x, Wx, Wh, bias, (const _Float16*)d_out,
                                         out, PbufF, zbufF);
  }
}

// Round 20
// 7217.190 us; speedup vs baseline: 3.6468x; 3.6468x over previous
//
#include <hip/hip_runtime.h>
#include <stdint.h>
#include <stddef.h>

// GRU (B=32, T=2048, I=H=512, fp32 in/out).
// Phase 1 (MFMA GEMM): gz|gr -> fp16 INTO d_out (row-aliased); gh -> d_ws.
// Phase 2 (R16 structure, proven 7.03 ms): persistent scan, 256 WGs =
//   8 slices x 32 batches, D=1 lean step:
//   - conflict-free b128 weight LDS [g][cc][col][sub][8]
//   - wave-local 8-lane shuffle z/r reduce, 2 barriers/step
//   - fp16 P exchange u32 {tag16|fp16} slice-major coalesced + f32 z u64
//   - agent-scope tagged exchange ONLY (R9/R10/R19: any poll servable by a
//     consumer-side cache livelocks; sc0 fast paths failed 3x independently)
//   Step = ~1.0us compute + ~2.2us fabric publish->detect RTT; latency floor
//   of the 2048-step cross-WG dependence chain (stagger/fusion/payload diets
//   all lose: R11,R14,R15,R17,R18).
// Fallback (!gh_mode): R8 scalar scan.

#define AGENT __HIP_MEMORY_SCOPE_AGENT

typedef _Float16 h2v __attribute__((ext_vector_type(2)));
typedef _Float16 half8 __attribute__((ext_vector_type(8)));
typedef float f32x4 __attribute__((ext_vector_type(4)));

__device__ __forceinline__ uint32_t pk2u(float a, float b) {
  h2v r; r[0] = (_Float16)a; r[1] = (_Float16)b;
  return __builtin_bit_cast(uint32_t, r);
}
__device__ __forceinline__ h2v bc2(uint32_t u) { return __builtin_bit_cast(h2v, u); }
__device__ __forceinline__ float dot2f(h2v a, h2v b, float c) {
#if __has_builtin(__builtin_amdgcn_fdot2)
  return __builtin_amdgcn_fdot2(a, b, c, false);
#else
  return fmaf((float)a[1], (float)b[1], fmaf((float)a[0], (float)b[0], c));
#endif
}
__device__ __forceinline__ float sigmoidf_(float x) { return 1.0f / (1.0f + __expf(-x)); }
__device__ __forceinline__ float tanhf_(float x) { return 1.0f - 2.0f / (1.0f + __expf(2.0f * x)); }

__device__ __forceinline__ uint32_t ald32(const uint32_t* p) {
  return __hip_atomic_load(p, __ATOMIC_RELAXED, AGENT);
}
__device__ __forceinline__ void ast32(uint32_t* p, uint32_t v) {
  __hip_atomic_store(p, v, __ATOMIC_RELAXED, AGENT);
}
__device__ __forceinline__ uint64_t ald64(const uint64_t* p) {
  return __hip_atomic_load(p, __ATOMIC_RELAXED, AGENT);
}
__device__ __forceinline__ void ast64(uint64_t* p, uint64_t v) {
  __hip_atomic_store(p, v, __ATOMIC_RELAXED, AGENT);
}
__device__ __forceinline__ float f16b2f(uint32_t w) {
  return (float)__builtin_bit_cast(_Float16, (unsigned short)(w & 0xffffu));
}

// ---------------- Phase 1: gate GEMM  [65536 x 512] @ [512 x N*128] -> fp16 ----------------
__global__ __launch_bounds__(256) void gemm_gx(const float* __restrict__ x,
                                               const float* __restrict__ Wx,
                                               const float* __restrict__ bias,
                                               _Float16* gzr,   // [65536][1024] (aliases out)
                                               _Float16* gh,    // [65536][512] in ws (opt)
                                               int nTN) {
  __shared__ alignas(16) _Float16 Alds[128 * 68];
  __shared__ alignas(16) _Float16 Blds[128 * 68];
  const int tid = threadIdx.x;
  const int bid = blockIdx.x;
  const int tm = bid / nTN, tn = bid % nTN;
  const int m0 = tm << 7, n0 = tn << 7;
  const int lane = tid & 63;
  const int wv = tid >> 6, wm = wv >> 1, wn = wv & 1;
  const int l15 = lane & 15, lhi = lane >> 4;
  f32x4 acc[4][4] = {};

  for (int k0 = 0; k0 < 512; k0 += 64) {
#pragma unroll
    for (int r = 0; r < 8; ++r) {
      int m = r * 16 + (tid >> 4);
      int k = (tid & 15) * 4;
      float4 v = *(const float4*)&x[(size_t)(m0 + m) * 512 + k0 + k];
      union { _Float16 h[4]; uint2 u; } cv;
      cv.h[0] = (_Float16)v.x; cv.h[1] = (_Float16)v.y;
      cv.h[2] = (_Float16)v.z; cv.h[3] = (_Float16)v.w;
      *(uint2*)&Alds[m * 68 + k] = cv.u;
    }
#pragma unroll
    for (int u = 0; u < 8; ++u) {
      int n = tid & 127;
      int k = (tid >> 7) * 32 + u * 4;
      int ng = n0 + n;
      const float* wp = Wx + ((size_t)(ng >> 9) << 18) + (size_t)(k0 + k) * 512 + (ng & 511);
      union { _Float16 h[4]; uint2 u2; } cv;
      cv.h[0] = (_Float16)wp[0];    cv.h[1] = (_Float16)wp[512];
      cv.h[2] = (_Float16)wp[1024]; cv.h[3] = (_Float16)wp[1536];
      *(uint2*)&Blds[n * 68 + k] = cv.u2;
    }
    __syncthreads();
#pragma unroll
    for (int kk = 0; kk < 2; ++kk) {
      int q = kk * 4 + lhi;
      half8 af[4], bf[4];
#pragma unroll
      for (int fm = 0; fm < 4; ++fm) {
        const _Float16* pa = &Alds[(wm * 64 + fm * 16 + l15) * 68 + q * 8];
        union { uint2 u[2]; half8 h; } cv;
        cv.u[0] = *(const uint2*)pa; cv.u[1] = *(const uint2*)(pa + 4);
        af[fm] = cv.h;
      }
#pragma unroll
      for (int fn = 0; fn < 4; ++fn) {
        const _Float16* pb = &Blds[(wn * 64 + fn * 16 + l15) * 68 + q * 8];
        union { uint2 u[2]; half8 h; } cv;
        cv.u[0] = *(const uint2*)pb; cv.u[1] = *(const uint2*)(pb + 4);
        bf[fn] = cv.h;
      }
#pragma unroll
      for (int fm = 0; fm < 4; ++fm)
#pragma unroll
        for (int fn = 0; fn < 4; ++fn)
          acc[fm][fn] = __builtin_amdgcn_mfma_f32_16x16x32_f16(af[fm], bf[fn], acc[fm][fn], 0, 0, 0);
    }
    __syncthreads();
  }
#pragma unroll
  for (int fn = 0; fn < 4; ++fn) {
    int col = n0 + wn * 64 + fn * 16 + l15;
    float bv = bias[col];
#pragma unroll
    for (int fm = 0; fm < 4; ++fm) {
#pragma unroll
      for (int q2 = 0; q2 < 4; ++q2) {
        int row = m0 + wm * 64 + fm * 16 + lhi * 4 + q2;
        _Float16 val = (_Float16)(acc[fm][fn][q2] + bv);
        if (n0 < 1024) gzr[(size_t)row * 1024 + col] = val;
        else           gh[(size_t)row * 512 + (col - 1024)] = val;
      }
    }
  }
}

// ---------------- Phase 2 (R16): lean D=1 persistent scan ----------------
__device__ __forceinline__ bool tagsok8(const uint32_t pv[8], uint64_t zv, uint32_t want) {
  bool ok = ((uint32_t)(zv >> 32) == want);
#pragma unroll
  for (int q = 0; q < 8; ++q) ok &= ((pv[q] >> 16) == want);
  return ok;
}

__global__ __launch_bounds__(512) void gru_scan3(
    const _Float16* gzr,            // [65536][1024] (aliases out!)
    const _Float16* ghg,            // [65536][512]
    const float* __restrict__ Wh,   // [3][512][512]
    float* out,                     // [32][2048][512] + [32][512]
    uint32_t* __restrict__ Pbuf,    // [2][32][8 slice][512 col] u32 {tag16|fp16}
    uint64_t* __restrict__ zbuf) {  // [2][32][512] u64 {tag32|f32}
  // wzK[g][cc][col][sub][8]: lane (col,sub) reads 16B at consecutive lane
  // addresses -> conflict-free b128. 128 KB.
  __shared__ alignas(16) _Float16 wzK[2 * 8 * 64 * 8 * 8];
  __shared__ alignas(16) _Float16 hA[512];   // full h_{t-1}
  __shared__ alignas(16) _Float16 rh[64];    // r*h for own 64 cols

  const int T = threadIdx.x;
  const int bid = blockIdx.x;     // 0..255
  const int s = bid >> 5;         // slice 0..7 -> K rows / z-r cols [s*64, s*64+64)
  const int b = bid & 31;         // batch; bids of batch b -> bid%8=b%8 (one XCD heuristic)
  const int c = T >> 3, sub = T & 7;
  const int gcol = s * 64 + c;

  // ---- weight fill: wzK entry (g,cc,col,sub)[e] = W_g[(cc*8+sub)*8+e][s*64+col] ----
  for (int g = 0; g < 2; ++g) {
    const float* W = Wh + (size_t)g * 262144;
    for (int idx = T; idx < 4096; idx += 512) {
      int cc = idx >> 9;
      int col = (idx >> 3) & 63;
      int sb = idx & 7;
      int kbase = (cc * 8 + sb) * 8;
      _Float16* dst = &wzK[(((g * 8 + cc) * 64 + col) * 8 + sb) * 8];
#pragma unroll
      for (int e = 0; e < 8; ++e)
        dst[e] = (_Float16)W[(size_t)(kbase + e) * 512 + s * 64 + col];
    }
  }
  // ---- candidate weights: 32 u32/thread (K rows = own 64 cols) ----
  uint32_t wh2[32];
  {
    const float* Whh = Wh + 524288;
#pragma unroll
    for (int i = 0; i < 32; ++i) {
      int kk = s * 64 + 2 * i;
      wh2[i] = pk2u(Whh[(size_t)kk * 512 + T], Whh[(size_t)(kk + 1) * 512 + T]);
    }
  }
  hA[T] = (_Float16)0.0f;
  float hreg = 0.f;

  const size_t rb = (size_t)b * 2048;
  float gh_p, gh_c = 0.f, gz_p = 0.f, gr_p = 0.f, gz_c = 0.f, gr_c = 0.f;
  gh_p = (float)ghg[rb * 512 + T];
  if (sub == 0) {
    gz_p = (float)gzr[rb * 1024 + gcol];
    gr_p = (float)gzr[rb * 1024 + 512 + gcol];
  }

  uint32_t* Pm = Pbuf + ((size_t)b * 8 + s) * 512 + T;  // + par*131072 (coalesced publish)
  const uint32_t* Pr = Pbuf + (size_t)b * 4096 + T;     // slice q at +q*512
  uint64_t* zm = zbuf + (size_t)b * 512 + gcol;         // + par*16384 (sub==0 publish)
  const uint64_t* zrd = zbuf + (size_t)b * 512 + T;

  uint32_t pv[8];
  uint64_t zv = 0;
#pragma unroll
  for (int q = 0; q < 8; ++q) pv[q] = 0;

  for (int t = 0; t < 2048; ++t) {
    const size_t poC = ((t - 1) & 1) ? 131072 : 0;
    const size_t zoC = ((t - 1) & 1) ? 16384 : 0;
    const size_t poN = (t & 1) ? 131072 : 0;
    const size_t zoN = (t & 1) ? 16384 : 0;
    const uint32_t want = (uint32_t)t;
    const uint32_t tagN = (uint32_t)(t + 1);

    // ---- combine step t-1 (pv/zv pre-issued at end of previous iter) ----
    if (t > 0) {
      while (!tagsok8(pv, zv, want)) {
        __builtin_amdgcn_s_sleep(2);
        if ((uint32_t)(zv >> 32) != want) zv = ald64(zrd + zoC);
#pragma unroll
        for (int q = 0; q < 8; ++q)
          if ((pv[q] >> 16) != want) pv[q] = ald32(Pr + poC + (size_t)q * 512);
      }
      float hsum = 0.f;
#pragma unroll
      for (int q = 0; q < 8; ++q) hsum += f16b2f(pv[q]);
      float zf = __uint_as_float((uint32_t)zv);
      float htil = tanhf_(gh_c + hsum);
      float hn = fmaf(zf, htil - hreg, hreg);
      if (s == 0) out[(rb + (t - 1)) * 512 + T] = hn;
      hreg = hn;
      hA[T] = (_Float16)hn;
    }
    gh_c = gh_p;
    gz_c = gz_p;
    gr_c = gr_p;
    __syncthreads();  // B1: hA(t-1) visible
    if (t < 2047) {
      size_t r1 = rb + t + 1;
      gh_p = (float)ghg[r1 * 512 + T];
      if (sub == 0) {
        gz_p = (float)gzr[r1 * 1024 + gcol];
        gr_p = (float)gzr[r1 * 1024 + 512 + gcol];
      }
    }

    // ---- z/r GEMV: thread (c,sub) covers K rows {(cc*8+sub)*8..+8, cc=0..7} ----
    float za = 0.f, ra = 0.f;
#pragma unroll
    for (int cc = 0; cc < 8; ++cc) {
      uint4 hu = *(const uint4*)&hA[(cc * 8 + sub) * 8];
      uint4 wz = *(const uint4*)&wzK[(((cc)*64 + c) * 8 + sub) * 8];
      uint4 wr = *(const uint4*)&wzK[(((8 + cc) * 64 + c) * 8 + sub) * 8];
      za = dot2f(bc2(hu.x), bc2(wz.x), za); za = dot2f(bc2(hu.y), bc2(wz.y), za);
      za = dot2f(bc2(hu.z), bc2(wz.z), za); za = dot2f(bc2(hu.w), bc2(wz.w), za);
      ra = dot2f(bc2(hu.x), bc2(wr.x), ra); ra = dot2f(bc2(hu.y), bc2(wr.y), ra);
      ra = dot2f(bc2(hu.z), bc2(wr.z), ra); ra = dot2f(bc2(hu.w), bc2(wr.w), ra);
    }
    // wave-local reduce over sub (lanes differ only in low 3 bits)
#pragma unroll
    for (int d = 1; d < 8; d <<= 1) {
      za += __shfl_xor(za, d);
      ra += __shfl_xor(ra, d);
    }
    if (sub == 0) {
      float z = sigmoidf_(za + gz_c);
      float r = sigmoidf_(ra + gr_c);
      rh[c] = (_Float16)(r * (float)hA[gcol]);
      ast64(zm + zoN, ((uint64_t)tagN << 32) | (uint32_t)__float_as_uint(z));
    }
    __syncthreads();  // B2: rh ready

    // ---- candidate K-slice (own 64 rows) -> publish P (coalesced u32) ----
    {
      float pa = 0.f;
#pragma unroll
      for (int i = 0; i < 16; ++i) {
        uint2 ru = *(const uint2*)&rh[4 * i];  // broadcast
        pa = dot2f(bc2(ru.x), bc2(wh2[2 * i]), pa);
        pa = dot2f(bc2(ru.y), bc2(wh2[2 * i + 1]), pa);
      }
      unsigned short pb = __builtin_bit_cast(unsigned short, (_Float16)pa);
      ast32(Pm + poN, (tagN << 16) | (uint32_t)pb);
    }
    // pre-issue next combine loads (parity poN)
    zv = ald64(zrd + zoN);
#pragma unroll
    for (int q = 0; q < 8; ++q) pv[q] = ald32(Pr + poN + (size_t)q * 512);
    __builtin_amdgcn_sched_barrier(0);
  }

  // ---- epilogue: combine step 2047 (parity 1, tag 2048) ----
  {
    const uint32_t want = 2048u;
    while (!tagsok8(pv, zv, want)) {
      __builtin_amdgcn_s_sleep(2);
      if ((uint32_t)(zv >> 32) != want) zv = ald64(zrd + 16384);
#pragma unroll
      for (int q = 0; q < 8; ++q)
        if ((pv[q] >> 16) != want) pv[q] = ald32(Pr + 131072 + (size_t)q * 512);
    }
    float hsum = 0.f;
#pragma unroll
    for (int q = 0; q < 8; ++q) hsum += f16b2f(pv[q]);
    float zf = __uint_as_float((uint32_t)zv);
    float htil = tanhf_(gh_c + hsum);
    float hn = fmaf(zf, htil - hreg, hreg);
    if (s == 0) {
      out[(rb + 2047) * 512 + T] = hn;
      out[(size_t)32 * 2048 * 512 + (size_t)b * 512 + T] = hn;
    }
  }
}

// ---------------- Fallback scan (R8 scalar, !gh_mode) ----------------
__global__ __launch_bounds__(512) void gru_scan_fb(
    const float* __restrict__ x, const float* __restrict__ Wx,
    const float* __restrict__ Wh, const float* __restrict__ bias,
    const _Float16* gzr, float* out,
    uint64_t* __restrict__ Pbuf, uint64_t* __restrict__ zbuf) {
  __shared__ alignas(16) float zrp[2][8][64];
  __shared__ alignas(16) _Float16 wzrL[2 * 64 * 516];
  __shared__ alignas(16) _Float16 h16[512];
  __shared__ alignas(16) _Float16 rh16[64];
  __shared__ alignas(16) _Float16 x16s[64];

  const int T = threadIdx.x;
  const int bid = blockIdx.x;
  const int xcd = bid & 7, ii = bid >> 3;
  const int batch = xcd * 4 + (ii >> 3);
  const int slice = ii & 7;
  const int wv = T >> 6, ln = T & 63, n = T;
  {
    const int cc = T & 63, kb = T >> 6;
#pragma unroll 4
    for (int g = 0; g < 2; ++g) {
      const float* W = Wh + (size_t)g * 262144 + slice * 64 + cc;
      for (int i = 0; i < 64; ++i) {
        int k = kb + 8 * i;
        wzrL[(g * 64 + cc) * 516 + k] = (_Float16)W[(size_t)k * 512];
      }
    }
  }
  uint32_t wh2[32], wx2[32];
  {
    const float* Whh = Wh + 524288;
    const float* Wxh = Wx + 524288;
#pragma unroll
    for (int jj = 0; jj < 32; ++jj) {
      int kk = slice * 64 + 2 * jj;
      wh2[jj] = pk2u(Whh[(size_t)kk * 512 + n], Whh[(size_t)(kk + 1) * 512 + n]);
      wx2[jj] = pk2u(Wxh[(size_t)kk * 512 + n], Wxh[(size_t)(kk + 1) * 512 + n]);
    }
  }
  const float bh = bias[1024 + n];
  float hreg = 0.0f;
  h16[T] = (_Float16)0.0f;
  const size_t rowbase = (size_t)batch * 2048;
  float gz_p = 0.f, gr_p = 0.f, gz_cur = 0.f, gr_cur = 0.f, x_p = 0.f;
  if (T < 64)       gz_p = (float)gzr[rowbase * 1024 + slice * 64 + T];
  else if (T < 128) gr_p = (float)gzr[rowbase * 1024 + 512 + slice * 64 + (T - 64)];
  if (T < 64) x_p = x[rowbase * 512 + slice * 64 + T];

  uint64_t* Pmine = Pbuf + ((size_t)batch * 8 + slice) * 512 + n;
  const uint64_t* Pread = Pbuf + ((size_t)batch * 8) * 512 + n;
  uint64_t* zmine = zbuf + (size_t)batch * 512 + slice * 64 + ln;
  const uint64_t* zread = zbuf + (size_t)batch * 512 + n;

  for (int t = 0; t < 2048; ++t) {
    if (t > 0) {
      const size_t po = ((t - 1) & 1) ? 131072 : 0;
      const size_t zo = ((t - 1) & 1) ? 16384 : 0;
      const uint32_t want = (uint32_t)t;
      uint64_t v[8];
#pragma unroll
      for (int g = 0; g < 8; ++g) v[g] = ald64(Pread + po + (size_t)g * 512);
      uint64_t zvv = ald64(zread + zo);
      for (;;) {
        bool ok = true;
        if ((uint32_t)(zvv >> 32) != want) { zvv = ald64(zread + zo); ok = false; }
#pragma unroll
        for (int g = 0; g < 8; ++g)
          if ((uint32_t)(v[g] >> 32) != want) { v[g] = ald64(Pread + po + (size_t)g * 512); ok = false; }
        if (ok) break;
        __builtin_amdgcn_s_sleep(1);
      }
      float hsum = 0.f;
#pragma unroll
      for (int g = 0; g < 8; ++g) hsum += __uint_as_float((uint32_t)v[g]);
      float zf = __uint_as_float((uint32_t)zvv);
      float htil = tanhf_(bh + hsum);
      float hn = fmaf(zf, htil - hreg, hreg);
      if (slice == 0) out[(rowbase + (t - 1)) * 512 + n] = hn;
      hreg = hn;
      h16[T] = (_Float16)hn;
    }
    gz_cur = gz_p; gr_cur = gr_p;
    if (T < 64) x16s[T] = (_Float16)x_p;
    __syncthreads();
    if (t < 2047) {
      size_t r1 = rowbase + t + 1;
      if (T < 64)       gz_p = (float)gzr[r1 * 1024 + slice * 64 + T];
      else if (T < 128) gr_p = (float)gzr[r1 * 1024 + 512 + slice * 64 + (T - 64)];
      if (T < 64) x_p = x[r1 * 512 + slice * 64 + T];
    }
    float za = 0.f, ra = 0.f;
    {
      const _Float16* wzp = &wzrL[ln * 516 + 64 * wv];
      const _Float16* wrp = &wzrL[(64 + ln) * 516 + 64 * wv];
      const _Float16* hp = &h16[64 * wv];
#pragma unroll
      for (int jj = 0; jj < 16; ++jj) {
        uint2 wzu = *(const uint2*)(wzp + 4 * jj);
        uint2 wru = *(const uint2*)(wrp + 4 * jj);
        uint2 hu = *(const uint2*)(hp + 4 * jj);
        za = dot2f(bc2(hu.x), bc2(wzu.x), za);
        za = dot2f(bc2(hu.y), bc2(wzu.y), za);
        ra = dot2f(bc2(hu.x), bc2(wru.x), ra);
        ra = dot2f(bc2(hu.y), bc2(wru.y), ra);
      }
    }
    zrp[0][wv][ln] = za;
    zrp[1][wv][ln] = ra;
    __syncthreads();
    const size_t po = (t & 1) ? 131072 : 0;
    const size_t zo = (t & 1) ? 16384 : 0;
    const uint64_t tagw = ((uint64_t)(uint32_t)(t + 1)) << 32;
    if (T < 128) {
      const int g = T >> 6, cc = T & 63;
      float sum = 0.f;
#pragma unroll
      for (int s2 = 0; s2 < 8; ++s2) sum += zrp[g][s2][cc];
      if (g == 0) {
        float z = sigmoidf_(sum + gz_cur);
        ast64(zmine + zo, tagw | (uint32_t)__float_as_uint(z));
      } else {
        float r = sigmoidf_(sum + gr_cur);
        rh16[cc] = (_Float16)(r * (float)h16[slice * 64 + cc]);
      }
    }
    __syncthreads();
    float pa = 0.f;
#pragma unroll
    for (int jj = 0; jj < 16; ++jj) {
      uint2 ru = *(const uint2*)&rh16[4 * jj];
      pa = dot2f(bc2(ru.x), bc2(wh2[2 * jj]), pa);
      pa = dot2f(bc2(ru.y), bc2(wh2[2 * jj + 1]), pa);
    }
#pragma unroll
    for (int jj = 0; jj < 16; ++jj) {
      uint2 xu = *(const uint2*)&x16s[4 * jj];
      pa = dot2f(bc2(xu.x), bc2(wx2[2 * jj]), pa);
      pa = dot2f(bc2(xu.y), bc2(wx2[2 * jj + 1]), pa);
    }
    ast64(Pmine + po, tagw | (uint32_t)__float_as_uint(pa));
    __syncthreads();
  }
  {
    const uint32_t want = 2048u;
    uint64_t v[8];
#pragma unroll
    for (int g = 0; g < 8; ++g) v[g] = ald64(Pread + 131072 + (size_t)g * 512);
    uint64_t zvv = ald64(zread + 16384);
    for (;;) {
      bool ok = true;
      if ((uint32_t)(zvv >> 32) != want) { zvv = ald64(zread + 16384); ok = false; }
#pragma unroll
      for (int g = 0; g < 8; ++g)
        if ((uint32_t)(v[g] >> 32) != want) { v[g] = ald64(Pread + 131072 + (size_t)g * 512); ok = false; }
      if (ok) break;
      __builtin_amdgcn_s_sleep(1);
    }
    float hsum = 0.f;
#pragma unroll
    for (int g = 0; g < 8; ++g) hsum += __uint_as_float((uint32_t)v[g]);
    float zf = __uint_as_float((uint32_t)zvv);
    float htil = tanhf_(bh + hsum);
    float hn = fmaf(zf, htil - hreg, hreg);
    if (slice == 0) {
      out[(rowbase + 2047) * 512 + n] = hn;
      out[(size_t)32 * 2048 * 512 + (size_t)batch * 512 + n] = hn;
    }
  }
}

extern "C" void kernel_launch(void* const* d_in, const int* in_sizes, int n_in,
                              void* d_out, int out_size, void* d_ws, size_t ws_size,
                              hipStream_t stream) {
  (void)in_sizes; (void)n_in; (void)out_size;
  const float* x    = (const float*)d_in[0];
  const float* Wx   = (const float*)d_in[1];
  const float* Wh   = (const float*)d_in[2];
  const float* bias = (const float*)d_in[3];
  float* out = (float*)d_out;
  char* ws = (char*)d_ws;

  // gh_mode: Pbuf u32 [2][32][8][512] = 1 MB | zbuf u64 [2][32][512] = 256 KB | gh @ 2621440
  // fallback: Pbuf u64 2 MB | zbuf u64 @ 2097152
  uint32_t* Pbuf3 = (uint32_t*)ws;
  uint64_t* zbuf3 = (uint64_t*)(ws + 1048576);
  uint64_t* PbufF = (uint64_t*)ws;
  uint64_t* zbufF = (uint64_t*)(ws + 2097152);
  _Float16* gh    = (_Float16*)(ws + 2621440);

  hipMemsetAsync(ws, 0, 2621440, stream);  // reset exchange tags (replay-safe)
  const bool gh_mode = ws_size >= (size_t)2621440 + 67108864ull;
  if (gh_mode) {
    gemm_gx<<<512 * 12, 256, 0, stream>>>(x, Wx, bias, (_Float16*)d_out, gh, 12);
    gru_scan3<<<256, 512, 0, stream>>>((const _Float16*)d_out, gh, Wh, out,
                                       Pbuf3, zbuf3);
  } else {
    gemm_gx<<<512 * 8, 256, 0, stream>>>(x, Wx, bias, (_Float16*)d_out, gh, 8);
    gru_scan_fb<<<256, 512, 0, stream>>>(x, Wx, Wh, bias, (const _Float16*)d_out,
                                         out, PbufF, zbufF);
  }
}